// Round 14
// baseline (290.631 us; speedup 1.0000x reference)
//
#include <hip/hip_runtime.h>

#define N_NODES 50000
#define N_EDGES 800000
#define NB_HIST 192
#define NPB 261            // nodes per hist block: 192*261 = 50112 >= 50000
#define E4 (N_EDGES / 4)   // 200000 int4s

typedef float f32x4 __attribute__((ext_vector_type(4)));
typedef float f32x2 __attribute__((ext_vector_type(2)));
typedef __bf16 bf16x8 __attribute__((ext_vector_type(8)));
typedef __bf16 bf16x4 __attribute__((ext_vector_type(4)));

#define CAST_N4 (N_NODES * 32)  // float4 count of x
#define PREP_ITEMS (CAST_N4 + 32768 + 65536 + 16384 + 8192 + 64)
#define PREP_BLOCKS ((PREP_ITEMS + 511) / 512)

// ---------------- hist via dst-partitioned LDS histograms (NO fabric atomics) ----------------
// Blocks [0,NB_HIST): block b owns nodes [b*NPB, b*NPB+NPB). Private LDS hist;
// each block streams the full dst array (3.2 MB, L2-resident broadcast read).
// rank[e] = LDS atomicAdd -> bijective rank within bucket; deg written directly.
// Blocks [NB_HIST,..): graph-independent prep (x_bf cast, weight transposes,
// bias add) -- co-resident with hist blocks (512thr+1KB LDS leaves 3 slots/CU),
// uses HBM while hist uses L2/VALU.
__global__ __launch_bounds__(512) void hist_prep(const int* __restrict__ dst, int* __restrict__ deg,
                                                 int* __restrict__ rank,
                                                 const float* __restrict__ x, __bf16* __restrict__ x_bf,
                                                 const float* __restrict__ W1, const float* __restrict__ W2,
                                                 const float* __restrict__ Wf, const float* __restrict__ Ws,
                                                 const float* __restrict__ bfb, const float* __restrict__ bsb,
                                                 __bf16* __restrict__ W1t, __bf16* __restrict__ W2t,
                                                 __bf16* __restrict__ Wft, __bf16* __restrict__ Wst,
                                                 float* __restrict__ bfinal) {
    int b = blockIdx.x;
    if (b < NB_HIST) {
        __shared__ int h[NPB];
        const int base = b * NPB;
        const unsigned count = (unsigned)min(NPB, N_NODES - base);
        for (int i = threadIdx.x; i < NPB; i += 512) h[i] = 0;
        __syncthreads();
        const int4* d4 = (const int4*)dst;
        for (int i = threadIdx.x; i < E4; i += 512) {
            int4 d = d4[i];
            int e = i * 4;
            unsigned r0 = (unsigned)(d.x - base);
            unsigned r1 = (unsigned)(d.y - base);
            unsigned r2 = (unsigned)(d.z - base);
            unsigned r3 = (unsigned)(d.w - base);
            if (r0 < count) rank[e + 0] = atomicAdd(&h[r0], 1);
            if (r1 < count) rank[e + 1] = atomicAdd(&h[r1], 1);
            if (r2 < count) rank[e + 2] = atomicAdd(&h[r2], 1);
            if (r3 < count) rank[e + 3] = atomicAdd(&h[r3], 1);
        }
        __syncthreads();
        for (int i = threadIdx.x; i < (int)count; i += 512) deg[base + i] = h[i];
        return;
    }
    int idx = (b - NB_HIST) * 512 + threadIdx.x;
    if (idx < CAST_N4) {
        float4 v = ((const float4*)x)[idx];
        bf16x4 a = {(__bf16)v.x, (__bf16)v.y, (__bf16)v.z, (__bf16)v.w};
        __builtin_nontemporal_store(a, (bf16x4*)x_bf + idx);
        return;
    }
    int j = idx - CAST_N4;
    if (j < 32768) {                       // W1t[n*128+k] = W1[k*256+n]
        int n = j >> 7, k = j & 127;
        W1t[j] = (__bf16)W1[k * 256 + n];
    } else if (j < 32768 + 65536) {        // W2t[n*256+k] = W2[k*256+n]
        int i = j - 32768;
        int n = i >> 8, k = i & 255;
        W2t[i] = (__bf16)W2[k * 256 + n];
    } else if (j < 32768 + 65536 + 16384) {  // Wft[n*256+k] = Wf[k*64+n]
        int i = j - (32768 + 65536);
        int n = i >> 8, k = i & 255;
        Wft[i] = (__bf16)Wf[k * 64 + n];
    } else if (j < 32768 + 65536 + 16384 + 8192) {  // Wst[n*128+k] = Ws[k*64+n]
        int i = j - (32768 + 65536 + 16384);
        int n = i >> 7, k = i & 127;
        Wst[i] = (__bf16)Ws[k * 64 + n];
    } else if (j < 32768 + 65536 + 16384 + 8192 + 64) {
        int i = j - (32768 + 65536 + 16384 + 8192);
        bfinal[i] = bfb[i] + bsb[i];
    }
}

__device__ __forceinline__ int wave_incl_scan(int x) {
    int lane = threadIdx.x & 63;
#pragma unroll
    for (int off = 1; off < 64; off <<= 1) {
        int y = __shfl_up(x, off, 64);
        if (lane >= off) x += y;
    }
    return x;
}

// exclusive-scan partials over 512-chunks; also emits dinv = rsqrt(deg+1)
__global__ void scan_partial_dinv(const int* __restrict__ in, int n,
                                  int* __restrict__ out_partial, int* __restrict__ blocksum,
                                  float* __restrict__ dinv) {
    __shared__ int wsum[8];
    int i = blockIdx.x * 512 + threadIdx.x;
    int v = (i < n) ? in[i] : 0;
    if (i < n) dinv[i] = rsqrtf((float)(v + 1));  // +1 self-loop
    int inc = wave_incl_scan(v);
    int lane = threadIdx.x & 63, wid = threadIdx.x >> 6;
    if (lane == 63) wsum[wid] = inc;
    __syncthreads();
    if (wid == 0) {
        int w = (lane < 8) ? wsum[lane] : 0;
        int wi = wave_incl_scan(w);
        if (lane < 8) wsum[lane] = wi;
    }
    __syncthreads();
    int woff = (wid == 0) ? 0 : wsum[wid - 1];
    if (i < n) out_partial[i] = woff + inc - v;
    if (threadIdx.x == 0) blocksum[blockIdx.x] = wsum[7];
}

// fused: every block scans the (<=128) block sums in LDS, then adds its offset.
__global__ void scan_add_fused(int* __restrict__ rowptr, int n,
                               const int* __restrict__ blocksum, int nb, int total) {
    __shared__ int sexc[128];
    __shared__ int w0tot;
    int t = threadIdx.x;
    if (t < 128) {
        int v = (t < nb) ? blocksum[t] : 0;
        int inc = wave_incl_scan(v);
        sexc[t] = inc - v;  // wave-exclusive
        if (t == 63) w0tot = inc;
    }
    __syncthreads();
    int b = blockIdx.x;
    int boff = sexc[b] + (b >= 64 ? w0tot : 0);
    int i = b * 512 + t;
    if (i < n) rowptr[i] += boff;
    if (i == 0) rowptr[n] = total;
}

#define HB 782  // fill blocks: 800000/4/256
#define XS_ITEMS (N_NODES * 16)  // bf16x8 items of x
#define XS_BLOCKS ((XS_ITEMS + 255) / 256)

// fill_csr (no atomics: pos = rowptr[d]+rank[e]) + x_s scaling, one dispatch.
__global__ void fill_xs(const int* __restrict__ src, const int* __restrict__ dst,
                        const int* __restrict__ rank,
                        const int* __restrict__ rowptr, int* __restrict__ csr_src,
                        const __bf16* __restrict__ x_bf, const float* __restrict__ dinv,
                        __bf16* __restrict__ x_s) {
    int b = blockIdx.x;
    if (b < HB) {
        int i = (b * 256 + threadIdx.x) * 4;
        if (i >= N_EDGES) return;
        int4 d = *(const int4*)(dst + i);
        int4 s = *(const int4*)(src + i);
        int4 r = *(const int4*)(rank + i);
        csr_src[rowptr[d.x] + r.x] = s.x;
        csr_src[rowptr[d.y] + r.y] = s.y;
        csr_src[rowptr[d.z] + r.z] = s.z;
        csr_src[rowptr[d.w] + r.w] = s.w;
        return;
    }
    int j = (b - HB) * 256 + threadIdx.x;
    if (j < XS_ITEMS) {
        bf16x8 v = ((const bf16x8*)x_bf)[j];
        float di = dinv[j >> 4];  // 16 bf16x8 per 128-wide row
        bf16x8 o;
#pragma unroll
        for (int k = 0; k < 8; ++k) o[k] = (__bf16)(di * (float)v[k]);
        ((bf16x8*)x_s)[j] = o;
    }
}

// ---------------- layer-1 aggregation (bf16 payload, half-wave, 16-edge unroll) ----------------

template <int V> struct VecSel;
template <> struct VecSel<4> { using T = bf16x4; };
template <> struct VecSel<8> { using T = bf16x8; };

template <int F>
__global__ __launch_bounds__(256) void aggregate_half(const __bf16* __restrict__ in_s, __bf16* __restrict__ out,
                                                      const int* __restrict__ rowptr, const int* __restrict__ csr_src,
                                                      const float* __restrict__ dinv) {
    constexpr int VB = F / 32;  // elems per lane within a half-wave row
    using VT = typename VecSel<VB>::T;
    int node = blockIdx.x * 4 + (threadIdx.x >> 6);
    int lane = threadIdx.x & 63;
    int lh = lane & 31;
    int half = lane >> 5;
    const __bf16* colbase = in_s + (size_t)lh * VB;

    float acc[VB] = {};
    if (half == 0) {  // self-loop row loaded by half A only
        VT v = *(const VT*)(colbase + (size_t)node * F);
#pragma unroll
        for (int j = 0; j < VB; ++j) acc[j] = (float)v[j];
    }

    int beg = rowptr[node], end = rowptr[node + 1];
    int e = beg;
    for (; e + 16 <= end; e += 16) {  // 8 gathers in flight per half-wave
        int ss[8];
#pragma unroll
        for (int k = 0; k < 8; ++k) ss[k] = csr_src[e + 2 * k + half];
        VT v[8];
#pragma unroll
        for (int k = 0; k < 8; ++k) v[k] = *(const VT*)(colbase + (size_t)ss[k] * F);
#pragma unroll
        for (int k = 0; k < 8; ++k)
#pragma unroll
            for (int j = 0; j < VB; ++j) acc[j] += (float)v[k][j];
    }
    for (; e + 8 <= end; e += 8) {
        int s0 = csr_src[e + half], s1 = csr_src[e + 2 + half];
        int s2 = csr_src[e + 4 + half], s3 = csr_src[e + 6 + half];
        VT v0 = *(const VT*)(colbase + (size_t)s0 * F);
        VT v1 = *(const VT*)(colbase + (size_t)s1 * F);
        VT v2 = *(const VT*)(colbase + (size_t)s2 * F);
        VT v3 = *(const VT*)(colbase + (size_t)s3 * F);
#pragma unroll
        for (int j = 0; j < VB; ++j) {
            acc[j] += (float)v0[j];
            acc[j] += (float)v1[j];
            acc[j] += (float)v2[j];
            acc[j] += (float)v3[j];
        }
    }
    for (; e + 2 <= end; e += 2) {
        int s = csr_src[e + half];
        VT v = *(const VT*)(colbase + (size_t)s * F);
#pragma unroll
        for (int j = 0; j < VB; ++j) acc[j] += (float)v[j];
    }
    if (e < end && half == 0) {  // odd tail: half A only
        int s = csr_src[e];
        VT v = *(const VT*)(colbase + (size_t)s * F);
#pragma unroll
        for (int j = 0; j < VB; ++j) acc[j] += (float)v[j];
    }

    float di = dinv[node];
    VT o;
#pragma unroll
    for (int j = 0; j < VB; ++j) {
        float t = acc[j] + __shfl_xor(acc[j], 32);
        o[j] = (__bf16)(di * t);
    }
    if (half == 0) __builtin_nontemporal_store(o, (VT*)(out + (size_t)node * F + lh * VB));
}

// ---------------- layer-2 aggregation (fp8 e4m3 payload, 16-edge unroll) ----------------

__global__ __launch_bounds__(256) void aggregate_fp8(const unsigned char* __restrict__ in_s, __bf16* __restrict__ out,
                                                     const int* __restrict__ rowptr, const int* __restrict__ csr_src,
                                                     const float* __restrict__ dinv) {
    constexpr int F = 256;
    int node = blockIdx.x * 4 + (threadIdx.x >> 6);
    int lane = threadIdx.x & 63;
    int lh = lane & 31;
    int half = lane >> 5;
    const unsigned char* colbase = in_s + lh * 8;

    float acc[8] = {};
    auto decode_acc = [&](uint2 v) {
        f32x2 p0 = __builtin_amdgcn_cvt_pk_f32_fp8(v.x, false);
        f32x2 p1 = __builtin_amdgcn_cvt_pk_f32_fp8(v.x, true);
        f32x2 p2 = __builtin_amdgcn_cvt_pk_f32_fp8(v.y, false);
        f32x2 p3 = __builtin_amdgcn_cvt_pk_f32_fp8(v.y, true);
        acc[0] += p0[0]; acc[1] += p0[1]; acc[2] += p1[0]; acc[3] += p1[1];
        acc[4] += p2[0]; acc[5] += p2[1]; acc[6] += p3[0]; acc[7] += p3[1];
    };

    if (half == 0) decode_acc(*(const uint2*)(colbase + (size_t)node * F));

    int beg = rowptr[node], end = rowptr[node + 1];
    int e = beg;
    for (; e + 16 <= end; e += 16) {  // 8 gathers in flight per half-wave
        int ss[8];
#pragma unroll
        for (int k = 0; k < 8; ++k) ss[k] = csr_src[e + 2 * k + half];
        uint2 v[8];
#pragma unroll
        for (int k = 0; k < 8; ++k) v[k] = *(const uint2*)(colbase + (size_t)ss[k] * F);
#pragma unroll
        for (int k = 0; k < 8; ++k) decode_acc(v[k]);
    }
    for (; e + 8 <= end; e += 8) {
        int s0 = csr_src[e + half], s1 = csr_src[e + 2 + half];
        int s2 = csr_src[e + 4 + half], s3 = csr_src[e + 6 + half];
        uint2 v0 = *(const uint2*)(colbase + (size_t)s0 * F);
        uint2 v1 = *(const uint2*)(colbase + (size_t)s1 * F);
        uint2 v2 = *(const uint2*)(colbase + (size_t)s2 * F);
        uint2 v3 = *(const uint2*)(colbase + (size_t)s3 * F);
        decode_acc(v0); decode_acc(v1); decode_acc(v2); decode_acc(v3);
    }
    for (; e + 2 <= end; e += 2) {
        int s = csr_src[e + half];
        decode_acc(*(const uint2*)(colbase + (size_t)s * F));
    }
    if (e < end && half == 0) decode_acc(*(const uint2*)(colbase + (size_t)csr_src[e] * F));

    float di = dinv[node];
    bf16x8 o;
#pragma unroll
    for (int j = 0; j < 8; ++j) {
        float t = acc[j] + __shfl_xor(acc[j], 32);
        o[j] = (__bf16)(di * t);
    }
    if (half == 0) __builtin_nontemporal_store(o, (bf16x8*)(out + (size_t)node * F + lh * 8));
}

// ---------------- MFMA bf16 GEMM staging (shared) ----------------
// LDS rows of 64 bf16 (8 x 16B granules), granule slot XOR-swizzled with (row&7).
// global_load_lds writes linearly; global SOURCE address pre-swizzled with the same
// involution so the swizzled read matches (rule 21).

template <int NROWS, int NTH>
__device__ __forceinline__ void stage_tile(const __bf16* __restrict__ src, int K, int row0, int rowclamp,
                                           int k0, char* lds) {
    int t = threadIdx.x;
#pragma unroll
    for (int p = 0; p < NROWS * 8 / NTH; ++p) {
        int G = p * NTH + t;
        int r = G >> 3, gp = G & 7;
        int g = gp ^ (r & 7);
        int gr = row0 + r;
        if (gr > rowclamp) gr = rowclamp;
        const __bf16* sp = src + (size_t)gr * K + k0 + g * 8;
        __builtin_amdgcn_global_load_lds((const __attribute__((address_space(1))) void*)sp,
                                         (__attribute__((address_space(3))) void*)(lds + G * 16), 16, 0, 0);
    }
}

// ---------------- wide GEMM: C[M x 256] = A[M x K] * Bt[256 x K]^T ----------------
// BM=64, 512 thr = 8 waves (1x8), wave tile 64x32, acc[4][2]; 2-phase dbuf.
// OUT_FP8: epilogue packs dinv*relu(.) pairs via v_cvt_pk_fp8_f32, byte stores.

template <bool SCALE, bool OUT_FP8>
__global__ __launch_bounds__(512, 4) void mfma_gemm_wide(const __bf16* __restrict__ A, const __bf16* __restrict__ Bt,
                                                         int K, const float* __restrict__ bias,
                                                         const float* __restrict__ dinv,
                                                         void* __restrict__ Cout, int M) {
    constexpr int N = 256;
    __shared__ alignas(16) char lds[81920];  // 2 x (A 8KB + B 32KB)
    const int lane = threadIdx.x & 63, wid = threadIdx.x >> 6;  // wid = wave col (0..7)
    const int row0 = blockIdx.x * 64;
    const int kg = lane >> 4, l15 = lane & 15;

    f32x4 acc[4][2];
#pragma unroll
    for (int mi = 0; mi < 4; ++mi)
#pragma unroll
        for (int ni = 0; ni < 2; ++ni) acc[mi][ni] = {0.f, 0.f, 0.f, 0.f};

    auto STAGE = [&](int buf, int k0) {
        char* base = lds + buf * 40960;
        stage_tile<64, 512>(A, K, row0, M - 1, k0, base);
        stage_tile<256, 512>(Bt, K, 0, N - 1, k0, base + 8192);
    };

    const int nt = K >> 6;
    STAGE(0, 0);
    __syncthreads();  // drains vmcnt: buf0 ready
    int cur = 0;
    for (int t = 0; t < nt; ++t) {
        if (t + 1 < nt) STAGE(cur ^ 1, (t + 1) * 64);  // overlap with compute below
        char* As = lds + cur * 40960;
        char* Bs = As + 8192;
        bf16x8 af[4][2], bfr[2][2];
#pragma unroll
        for (int mi = 0; mi < 4; ++mi) {
            int r = mi * 16 + l15;
#pragma unroll
            for (int kf = 0; kf < 2; ++kf) {
                int slot = (kf * 4 + kg) ^ (r & 7);
                af[mi][kf] = *(const bf16x8*)(As + r * 128 + slot * 16);
            }
        }
#pragma unroll
        for (int ni = 0; ni < 2; ++ni) {
            int r = wid * 32 + ni * 16 + l15;
#pragma unroll
            for (int kf = 0; kf < 2; ++kf) {
                int slot = (kf * 4 + kg) ^ (r & 7);
                bfr[ni][kf] = *(const bf16x8*)(Bs + r * 128 + slot * 16);
            }
        }
#pragma unroll
        for (int mi = 0; mi < 4; ++mi)
#pragma unroll
            for (int ni = 0; ni < 2; ++ni)
#pragma unroll
                for (int kf = 0; kf < 2; ++kf)
                    acc[mi][ni] = __builtin_amdgcn_mfma_f32_16x16x32_bf16(af[mi][kf], bfr[ni][kf],
                                                                          acc[mi][ni], 0, 0, 0);
        __syncthreads();
        cur ^= 1;
    }

    // C/D layout: col = lane&15, row = (lane>>4)*4 + q
#pragma unroll
    for (int mi = 0; mi < 4; ++mi) {
#pragma unroll
        for (int q = 0; q < 4; ++q) {
            int gr = row0 + mi * 16 + kg * 4 + q;
            if (gr >= M) continue;
            float sc = SCALE ? dinv[gr] : 1.0f;
            int col0 = wid * 32 + l15;
            float v0 = fmaxf(acc[mi][0][q] + bias[col0], 0.f);
            float v1 = fmaxf(acc[mi][1][q] + bias[col0 + 16], 0.f);
            if (SCALE) { v0 *= sc; v1 *= sc; }
            if constexpr (OUT_FP8) {
                int w = __builtin_amdgcn_cvt_pk_fp8_f32(v0, v1, 0, false);
                unsigned char* Cp = (unsigned char*)Cout + (size_t)gr * N;
                Cp[col0] = (unsigned char)(w & 0xff);
                Cp[col0 + 16] = (unsigned char)((w >> 8) & 0xff);
            } else {
                __bf16* Cp = (__bf16*)Cout + (size_t)gr * N;
                Cp[col0] = (__bf16)v0;
                Cp[col0 + 16] = (__bf16)v1;
            }
        }
    }
}

// ---------------- final GEMM: out[M x 64] = A1*B1t^T + A2*B2t^T + bias (f32 out) ----------------
// BM=64, 256 thr = 4 waves (2x2), wave tile 32x32, acc[2][2]; dual-K flattened, dbuf.

__global__ __launch_bounds__(256, 4) void mfma_gemm_final(const __bf16* __restrict__ A1, const __bf16* __restrict__ B1t, int K1,
                                                          const __bf16* __restrict__ A2, const __bf16* __restrict__ B2t, int K2,
                                                          const float* __restrict__ bias, float* __restrict__ Cout, int M) {
    constexpr int N = 64;
    __shared__ alignas(16) char lds[32768];  // 2 x (A 8KB + B 8KB)
    const int lane = threadIdx.x & 63, wid = threadIdx.x >> 6;
    const int wm = wid >> 1, wn = wid & 1;
    const int row0 = blockIdx.x * 64;
    const int kg = lane >> 4, l15 = lane & 15;

    f32x4 acc[2][2];
#pragma unroll
    for (int mi = 0; mi < 2; ++mi)
#pragma unroll
        for (int ni = 0; ni < 2; ++ni) acc[mi][ni] = {0.f, 0.f, 0.f, 0.f};

    const int nt1 = K1 >> 6, nt = nt1 + (K2 >> 6);
    auto STAGE = [&](int buf, int tile) {
        const __bf16* A = (tile < nt1) ? A1 : A2;
        const __bf16* Bt = (tile < nt1) ? B1t : B2t;
        int K = (tile < nt1) ? K1 : K2;
        int k0 = ((tile < nt1) ? tile : tile - nt1) * 64;
        char* base = lds + buf * 16384;
        stage_tile<64, 256>(A, K, row0, M - 1, k0, base);
        stage_tile<64, 256>(Bt, K, 0, N - 1, k0, base + 8192);
    };

    STAGE(0, 0);
    __syncthreads();
    int cur = 0;
    for (int t = 0; t < nt; ++t) {
        if (t + 1 < nt) STAGE(cur ^ 1, t + 1);
        char* As = lds + cur * 16384;
        char* Bs = As + 8192;
        bf16x8 af[2][2], bfr[2][2];
#pragma unroll
        for (int mi = 0; mi < 2; ++mi) {
            int r = wm * 32 + mi * 16 + l15;
#pragma unroll
            for (int kf = 0; kf < 2; ++kf) {
                int slot = (kf * 4 + kg) ^ (r & 7);
                af[mi][kf] = *(const bf16x8*)(As + r * 128 + slot * 16);
            }
        }
#pragma unroll
        for (int ni = 0; ni < 2; ++ni) {
            int r = wn * 32 + ni * 16 + l15;
#pragma unroll
            for (int kf = 0; kf < 2; ++kf) {
                int slot = (kf * 4 + kg) ^ (r & 7);
                bfr[ni][kf] = *(const bf16x8*)(Bs + r * 128 + slot * 16);
            }
        }
#pragma unroll
        for (int mi = 0; mi < 2; ++mi)
#pragma unroll
            for (int ni = 0; ni < 2; ++ni)
#pragma unroll
                for (int kf = 0; kf < 2; ++kf)
                    acc[mi][ni] = __builtin_amdgcn_mfma_f32_16x16x32_bf16(af[mi][kf], bfr[ni][kf],
                                                                          acc[mi][ni], 0, 0, 0);
        __syncthreads();
        cur ^= 1;
    }

#pragma unroll
    for (int mi = 0; mi < 2; ++mi) {
#pragma unroll
        for (int ni = 0; ni < 2; ++ni) {
            int col = wn * 32 + ni * 16 + l15;
            float bv = bias[col];
#pragma unroll
            for (int q = 0; q < 4; ++q) {
                int gr = row0 + wm * 32 + mi * 16 + kg * 4 + q;
                if (gr < M) Cout[(size_t)gr * N + col] = acc[mi][ni][q] + bv;
            }
        }
    }
}

// ---------------- launch ----------------

extern "C" void kernel_launch(void* const* d_in, const int* in_sizes, int n_in,
                              void* d_out, int out_size, void* d_ws, size_t ws_size,
                              hipStream_t stream) {
    const float* x  = (const float*)d_in[0];
    const int*   ei = (const int*)d_in[1];
    const int*   src = ei;
    const int*   dst = ei + N_EDGES;
    const float* W1 = (const float*)d_in[2];
    const float* b1 = (const float*)d_in[3];
    const float* W2 = (const float*)d_in[4];
    const float* b2 = (const float*)d_in[5];
    const float* Wf = (const float*)d_in[6];
    const float* bf = (const float*)d_in[7];
    const float* Ws = (const float*)d_in[8];
    const float* bs = (const float*)d_in[9];
    float* out = (float*)d_out;

    char* ws = (char*)d_ws;
    size_t off = 0;
    auto alloc = [&](size_t bytes) -> void* {
        void* p = ws + off;
        off += (bytes + 255) & ~(size_t)255;
        return p;
    };
    int*           deg      = (int*)alloc(N_NODES * 4);
    int*           rank     = (int*)alloc(N_EDGES * 4);   // per-edge rank within dst bucket
    int*           rowptr   = (int*)alloc((N_NODES + 1) * 4);
    float*         dinv     = (float*)alloc(N_NODES * 4);
    int*           blocksum = (int*)alloc(4096);
    int*           csr      = (int*)alloc(N_EDGES * 4);
    __bf16*        x_bf     = (__bf16*)alloc((size_t)N_NODES * 128 * 2);  // unscaled (skip GEMM)
    __bf16*        x_s      = (__bf16*)alloc((size_t)N_NODES * 128 * 2);  // dinv-scaled (agg1 input)
    __bf16*        W1t      = (__bf16*)alloc(128 * 256 * 2);
    __bf16*        W2t      = (__bf16*)alloc(256 * 256 * 2);
    __bf16*        Wft      = (__bf16*)alloc(256 * 64 * 2);
    __bf16*        Wst      = (__bf16*)alloc(128 * 64 * 2);
    float*         bfinal   = (float*)alloc(64 * 4);
    __bf16*        bufP1    = (__bf16*)alloc((size_t)N_NODES * 256 * 2);  // agg1 out (128-wide), later h2
    unsigned char* bufP2    = (unsigned char*)alloc((size_t)N_NODES * 256);  // h1_s in fp8 e4m3
    __bf16*        bufP3    = (__bf16*)alloc((size_t)N_NODES * 256 * 2);  // agg2 out (bf16)

    // hist (dst-partitioned LDS histograms, no fabric atomics) + prep co-scheduled
    hist_prep<<<NB_HIST + PREP_BLOCKS, 512, 0, stream>>>(dst, deg, rank, x, x_bf,
                                                         W1, W2, Wf, Ws, bf, bs,
                                                         W1t, W2t, Wft, Wst, bfinal);

    int nb = (N_NODES + 511) / 512;  // 98
    scan_partial_dinv<<<nb, 512, 0, stream>>>(deg, N_NODES, rowptr, blocksum, dinv);
    scan_add_fused<<<nb, 512, 0, stream>>>(rowptr, N_NODES, blocksum, nb, N_EDGES);

    // CSR scatter (no atomics) co-scheduled with x_s scaling
    fill_xs<<<HB + XS_BLOCKS, 256, 0, stream>>>(src, dst, rank, rowptr, csr, x_bf, dinv, x_s);

    const int gm64 = (N_NODES + 63) / 64;  // 782

    // layer 1: agg1 = Ahat x (pre-scaled x_s); h1_s = fp8(dinv * relu(agg1 @ W1 + b1))
    aggregate_half<128><<<(N_NODES + 3) / 4, 256, 0, stream>>>(x_s, bufP1, rowptr, csr, dinv);
    mfma_gemm_wide<true, true><<<gm64, 512, 0, stream>>>(bufP1, W1t, 128, b1, dinv, bufP2, N_NODES);

    // layer 2: agg2 = dinv * (sum of fp8 h1_s + self); h2 = relu(agg2 @ W2 + b2)
    aggregate_fp8<<<(N_NODES + 3) / 4, 256, 0, stream>>>(bufP2, bufP3, rowptr, csr, dinv);
    mfma_gemm_wide<false, false><<<gm64, 512, 0, stream>>>(bufP3, W2t, 256, b2, nullptr, bufP1, N_NODES);

    // out = h2 @ Wf + x @ Ws + (bf + bs)
    mfma_gemm_final<<<gm64, 256, 0, stream>>>(bufP1, Wft, 256, x_bf, Wst, 128, bfinal, out, N_NODES);
}

// Round 15
// 191.283 us; speedup vs baseline: 1.5194x; 1.5194x over previous
//
#include <hip/hip_runtime.h>

#define N_NODES 50000
#define N_EDGES 800000
#define HB 782  // hist/fill blocks: 800000/4/256 rounded up

typedef float f32x4 __attribute__((ext_vector_type(4)));
typedef float f32x2 __attribute__((ext_vector_type(2)));
typedef __bf16 bf16x8 __attribute__((ext_vector_type(8)));
typedef __bf16 bf16x4 __attribute__((ext_vector_type(4)));

// ---------------- graph preprocessing ----------------

// custom zero-fill (rocclr fill kernel measured 40us for 200KB)
__global__ void zero_deg(int4* __restrict__ p, int n4) {
    int i = blockIdx.x * blockDim.x + threadIdx.x;
    if (i < n4) p[i] = make_int4(0, 0, 0, 0);
}

#define CAST_N4 (N_NODES * 32)  // float4 count of x
#define PREP_ITEMS (CAST_N4 + 32768 + 65536 + 16384 + 8192 + 64)
#define PREP_BLOCKS ((PREP_ITEMS + 255) / 256)

// MEGA-PREP (R13, measured ~45us): blocks [0,HB) do hist+rank (fabric-atomic
// bound, ~0% VALU/HBM); blocks [HB,..) do graph-independent prep (x_bf cast,
// weight transposes, bias add) hidden under the atomic shadow.
__global__ void mega_prep(const int* __restrict__ dst, int* __restrict__ deg,
                          int* __restrict__ rank,
                          const float* __restrict__ x, __bf16* __restrict__ x_bf,
                          const float* __restrict__ W1, const float* __restrict__ W2,
                          const float* __restrict__ Wf, const float* __restrict__ Ws,
                          const float* __restrict__ bfb, const float* __restrict__ bsb,
                          __bf16* __restrict__ W1t, __bf16* __restrict__ W2t,
                          __bf16* __restrict__ Wft, __bf16* __restrict__ Wst,
                          float* __restrict__ bfinal) {
    int b = blockIdx.x;
    if (b < HB) {
        int i = (b * 256 + threadIdx.x) * 4;
        if (i >= N_EDGES) return;
        int4 d = *(const int4*)(dst + i);
        int4 r;
        r.x = atomicAdd(&deg[d.x], 1);
        r.y = atomicAdd(&deg[d.y], 1);
        r.z = atomicAdd(&deg[d.z], 1);
        r.w = atomicAdd(&deg[d.w], 1);
        *(int4*)(rank + i) = r;
        return;
    }
    int idx = (b - HB) * 256 + threadIdx.x;
    if (idx < CAST_N4) {
        float4 v = ((const float4*)x)[idx];
        bf16x4 a = {(__bf16)v.x, (__bf16)v.y, (__bf16)v.z, (__bf16)v.w};
        __builtin_nontemporal_store(a, (bf16x4*)x_bf + idx);
        return;
    }
    int j = idx - CAST_N4;
    if (j < 32768) {                       // W1t[n*128+k] = W1[k*256+n]
        int n = j >> 7, k = j & 127;
        W1t[j] = (__bf16)W1[k * 256 + n];
    } else if (j < 32768 + 65536) {        // W2t[n*256+k] = W2[k*256+n]
        int i = j - 32768;
        int n = i >> 8, k = i & 255;
        W2t[i] = (__bf16)W2[k * 256 + n];
    } else if (j < 32768 + 65536 + 16384) {  // Wft[n*256+k] = Wf[k*64+n]
        int i = j - (32768 + 65536);
        int n = i >> 8, k = i & 255;
        Wft[i] = (__bf16)Wf[k * 64 + n];
    } else if (j < 32768 + 65536 + 16384 + 8192) {  // Wst[n*128+k] = Ws[k*64+n]
        int i = j - (32768 + 65536 + 16384);
        int n = i >> 7, k = i & 127;
        Wst[i] = (__bf16)Ws[k * 64 + n];
    } else if (j < 32768 + 65536 + 16384 + 8192 + 64) {
        int i = j - (32768 + 65536 + 16384 + 8192);
        bfinal[i] = bfb[i] + bsb[i];
    }
}

__device__ __forceinline__ int wave_incl_scan(int x) {
    int lane = threadIdx.x & 63;
#pragma unroll
    for (int off = 1; off < 64; off <<= 1) {
        int y = __shfl_up(x, off, 64);
        if (lane >= off) x += y;
    }
    return x;
}

// exclusive-scan partials over 512-chunks; also emits dinv = rsqrt(deg+1)
__global__ void scan_partial_dinv(const int* __restrict__ in, int n,
                                  int* __restrict__ out_partial, int* __restrict__ blocksum,
                                  float* __restrict__ dinv) {
    __shared__ int wsum[8];
    int i = blockIdx.x * 512 + threadIdx.x;
    int v = (i < n) ? in[i] : 0;
    if (i < n) dinv[i] = rsqrtf((float)(v + 1));  // +1 self-loop
    int inc = wave_incl_scan(v);
    int lane = threadIdx.x & 63, wid = threadIdx.x >> 6;
    if (lane == 63) wsum[wid] = inc;
    __syncthreads();
    if (wid == 0) {
        int w = (lane < 8) ? wsum[lane] : 0;
        int wi = wave_incl_scan(w);
        if (lane < 8) wsum[lane] = wi;
    }
    __syncthreads();
    int woff = (wid == 0) ? 0 : wsum[wid - 1];
    if (i < n) out_partial[i] = woff + inc - v;
    if (threadIdx.x == 0) blocksum[blockIdx.x] = wsum[7];
}

#define SCAN_NB 98  // (50000+511)/512
#define XS_ITEMS (N_NODES * 16)  // bf16x8 items of x
#define XS_BLOCKS ((XS_ITEMS + 511) / 512)

// fused: blocks [0,SCAN_NB) scan the block sums in LDS and finalize rowptr;
// blocks [SCAN_NB,..) compute x_s = dinv * x_bf (dinv ready after scan_partial)
// -- hides the x_s traffic under the latency-bound scan and shortens fill.
__global__ __launch_bounds__(512) void scan_add_xs(int* __restrict__ rowptr, int n,
                                                   const int* __restrict__ blocksum, int nb, int total,
                                                   const __bf16* __restrict__ x_bf,
                                                   const float* __restrict__ dinv,
                                                   __bf16* __restrict__ x_s) {
    int b = blockIdx.x;
    if (b < SCAN_NB) {
        __shared__ int sexc[128];
        __shared__ int w0tot;
        int t = threadIdx.x;
        if (t < 128) {
            int v = (t < nb) ? blocksum[t] : 0;
            int inc = wave_incl_scan(v);
            sexc[t] = inc - v;  // wave-exclusive
            if (t == 63) w0tot = inc;
        }
        __syncthreads();
        int boff = sexc[b] + (b >= 64 ? w0tot : 0);
        int i = b * 512 + t;
        if (i < n) rowptr[i] += boff;
        if (i == 0) rowptr[n] = total;
        return;
    }
    int j = (b - SCAN_NB) * 512 + threadIdx.x;
    if (j < XS_ITEMS) {
        bf16x8 v = ((const bf16x8*)x_bf)[j];
        float di = dinv[j >> 4];  // 16 bf16x8 per 128-wide row
        bf16x8 o;
#pragma unroll
        for (int k = 0; k < 8; ++k) o[k] = (__bf16)(di * (float)v[k]);
        ((bf16x8*)x_s)[j] = o;
    }
}

// fill_csr: NO atomics, pos = rowptr[d] + rank[e]. Pure scatter.
__global__ void fill_csr(const int* __restrict__ src, const int* __restrict__ dst,
                         const int* __restrict__ rank,
                         const int* __restrict__ rowptr, int* __restrict__ csr_src) {
    int i = (blockIdx.x * blockDim.x + threadIdx.x) * 4;
    if (i >= N_EDGES) return;
    int4 d = *(const int4*)(dst + i);
    int4 s = *(const int4*)(src + i);
    int4 r = *(const int4*)(rank + i);
    csr_src[rowptr[d.x] + r.x] = s.x;
    csr_src[rowptr[d.y] + r.y] = s.y;
    csr_src[rowptr[d.z] + r.z] = s.z;
    csr_src[rowptr[d.w] + r.w] = s.w;
}

// ---------------- layer-1 aggregation (bf16 payload, half-wave, 16-edge unroll) ----------------

template <int V> struct VecSel;
template <> struct VecSel<4> { using T = bf16x4; };
template <> struct VecSel<8> { using T = bf16x8; };

template <int F>
__global__ __launch_bounds__(256) void aggregate_half(const __bf16* __restrict__ in_s, __bf16* __restrict__ out,
                                                      const int* __restrict__ rowptr, const int* __restrict__ csr_src,
                                                      const float* __restrict__ dinv) {
    constexpr int VB = F / 32;  // elems per lane within a half-wave row
    using VT = typename VecSel<VB>::T;
    int node = blockIdx.x * 4 + (threadIdx.x >> 6);
    int lane = threadIdx.x & 63;
    int lh = lane & 31;
    int half = lane >> 5;
    const __bf16* colbase = in_s + (size_t)lh * VB;

    float acc[VB] = {};
    if (half == 0) {  // self-loop row loaded by half A only
        VT v = *(const VT*)(colbase + (size_t)node * F);
#pragma unroll
        for (int j = 0; j < VB; ++j) acc[j] = (float)v[j];
    }

    int beg = rowptr[node], end = rowptr[node + 1];
    int e = beg;
    for (; e + 16 <= end; e += 16) {  // 8 gathers in flight per half-wave
        int ss[8];
#pragma unroll
        for (int k = 0; k < 8; ++k) ss[k] = csr_src[e + 2 * k + half];
        VT v[8];
#pragma unroll
        for (int k = 0; k < 8; ++k) v[k] = *(const VT*)(colbase + (size_t)ss[k] * F);
#pragma unroll
        for (int k = 0; k < 8; ++k)
#pragma unroll
            for (int j = 0; j < VB; ++j) acc[j] += (float)v[k][j];
    }
    for (; e + 8 <= end; e += 8) {
        int s0 = csr_src[e + half], s1 = csr_src[e + 2 + half];
        int s2 = csr_src[e + 4 + half], s3 = csr_src[e + 6 + half];
        VT v0 = *(const VT*)(colbase + (size_t)s0 * F);
        VT v1 = *(const VT*)(colbase + (size_t)s1 * F);
        VT v2 = *(const VT*)(colbase + (size_t)s2 * F);
        VT v3 = *(const VT*)(colbase + (size_t)s3 * F);
#pragma unroll
        for (int j = 0; j < VB; ++j) {
            acc[j] += (float)v0[j];
            acc[j] += (float)v1[j];
            acc[j] += (float)v2[j];
            acc[j] += (float)v3[j];
        }
    }
    for (; e + 2 <= end; e += 2) {
        int s = csr_src[e + half];
        VT v = *(const VT*)(colbase + (size_t)s * F);
#pragma unroll
        for (int j = 0; j < VB; ++j) acc[j] += (float)v[j];
    }
    if (e < end && half == 0) {  // odd tail: half A only
        int s = csr_src[e];
        VT v = *(const VT*)(colbase + (size_t)s * F);
#pragma unroll
        for (int j = 0; j < VB; ++j) acc[j] += (float)v[j];
    }

    float di = dinv[node];
    VT o;
#pragma unroll
    for (int j = 0; j < VB; ++j) {
        float t = acc[j] + __shfl_xor(acc[j], 32);
        o[j] = (__bf16)(di * t);
    }
    if (half == 0) __builtin_nontemporal_store(o, (VT*)(out + (size_t)node * F + lh * VB));
}

// ---------------- layer-2 aggregation (fp8 e4m3 payload, 16-edge unroll) ----------------

__global__ __launch_bounds__(256) void aggregate_fp8(const unsigned char* __restrict__ in_s, __bf16* __restrict__ out,
                                                     const int* __restrict__ rowptr, const int* __restrict__ csr_src,
                                                     const float* __restrict__ dinv) {
    constexpr int F = 256;
    int node = blockIdx.x * 4 + (threadIdx.x >> 6);
    int lane = threadIdx.x & 63;
    int lh = lane & 31;
    int half = lane >> 5;
    const unsigned char* colbase = in_s + lh * 8;

    float acc[8] = {};
    auto decode_acc = [&](uint2 v) {
        f32x2 p0 = __builtin_amdgcn_cvt_pk_f32_fp8(v.x, false);
        f32x2 p1 = __builtin_amdgcn_cvt_pk_f32_fp8(v.x, true);
        f32x2 p2 = __builtin_amdgcn_cvt_pk_f32_fp8(v.y, false);
        f32x2 p3 = __builtin_amdgcn_cvt_pk_f32_fp8(v.y, true);
        acc[0] += p0[0]; acc[1] += p0[1]; acc[2] += p1[0]; acc[3] += p1[1];
        acc[4] += p2[0]; acc[5] += p2[1]; acc[6] += p3[0]; acc[7] += p3[1];
    };

    if (half == 0) decode_acc(*(const uint2*)(colbase + (size_t)node * F));

    int beg = rowptr[node], end = rowptr[node + 1];
    int e = beg;
    for (; e + 16 <= end; e += 16) {  // 8 gathers in flight per half-wave
        int ss[8];
#pragma unroll
        for (int k = 0; k < 8; ++k) ss[k] = csr_src[e + 2 * k + half];
        uint2 v[8];
#pragma unroll
        for (int k = 0; k < 8; ++k) v[k] = *(const uint2*)(colbase + (size_t)ss[k] * F);
#pragma unroll
        for (int k = 0; k < 8; ++k) decode_acc(v[k]);
    }
    for (; e + 8 <= end; e += 8) {
        int s0 = csr_src[e + half], s1 = csr_src[e + 2 + half];
        int s2 = csr_src[e + 4 + half], s3 = csr_src[e + 6 + half];
        uint2 v0 = *(const uint2*)(colbase + (size_t)s0 * F);
        uint2 v1 = *(const uint2*)(colbase + (size_t)s1 * F);
        uint2 v2 = *(const uint2*)(colbase + (size_t)s2 * F);
        uint2 v3 = *(const uint2*)(colbase + (size_t)s3 * F);
        decode_acc(v0); decode_acc(v1); decode_acc(v2); decode_acc(v3);
    }
    for (; e + 2 <= end; e += 2) {
        int s = csr_src[e + half];
        decode_acc(*(const uint2*)(colbase + (size_t)s * F));
    }
    if (e < end && half == 0) decode_acc(*(const uint2*)(colbase + (size_t)csr_src[e] * F));

    float di = dinv[node];
    bf16x8 o;
#pragma unroll
    for (int j = 0; j < 8; ++j) {
        float t = acc[j] + __shfl_xor(acc[j], 32);
        o[j] = (__bf16)(di * t);
    }
    if (half == 0) __builtin_nontemporal_store(o, (bf16x8*)(out + (size_t)node * F + lh * 8));
}

// ---------------- MFMA bf16 GEMM staging (shared) ----------------
// LDS rows of 64 bf16 (8 x 16B granules), granule slot XOR-swizzled with (row&7).
// global_load_lds writes linearly; global SOURCE address pre-swizzled with the same
// involution so the swizzled read matches (rule 21).

template <int NROWS, int NTH>
__device__ __forceinline__ void stage_tile(const __bf16* __restrict__ src, int K, int row0, int rowclamp,
                                           int k0, char* lds) {
    int t = threadIdx.x;
#pragma unroll
    for (int p = 0; p < NROWS * 8 / NTH; ++p) {
        int G = p * NTH + t;
        int r = G >> 3, gp = G & 7;
        int g = gp ^ (r & 7);
        int gr = row0 + r;
        if (gr > rowclamp) gr = rowclamp;
        const __bf16* sp = src + (size_t)gr * K + k0 + g * 8;
        __builtin_amdgcn_global_load_lds((const __attribute__((address_space(1))) void*)sp,
                                         (__attribute__((address_space(3))) void*)(lds + G * 16), 16, 0, 0);
    }
}

// ---------------- wide GEMM: C[M x 256] = A[M x K] * Bt[256 x K]^T ----------------
// BM=64, 512 thr = 8 waves (1x8), wave tile 64x32, acc[4][2]; 2-phase dbuf.
// OUT_FP8: epilogue packs dinv*relu(.) pairs via v_cvt_pk_fp8_f32, byte stores.

template <bool SCALE, bool OUT_FP8>
__global__ __launch_bounds__(512, 4) void mfma_gemm_wide(const __bf16* __restrict__ A, const __bf16* __restrict__ Bt,
                                                         int K, const float* __restrict__ bias,
                                                         const float* __restrict__ dinv,
                                                         void* __restrict__ Cout, int M) {
    constexpr int N = 256;
    __shared__ alignas(16) char lds[81920];  // 2 x (A 8KB + B 32KB)
    const int lane = threadIdx.x & 63, wid = threadIdx.x >> 6;  // wid = wave col (0..7)
    const int row0 = blockIdx.x * 64;
    const int kg = lane >> 4, l15 = lane & 15;

    f32x4 acc[4][2];
#pragma unroll
    for (int mi = 0; mi < 4; ++mi)
#pragma unroll
        for (int ni = 0; ni < 2; ++ni) acc[mi][ni] = {0.f, 0.f, 0.f, 0.f};

    auto STAGE = [&](int buf, int k0) {
        char* base = lds + buf * 40960;
        stage_tile<64, 512>(A, K, row0, M - 1, k0, base);
        stage_tile<256, 512>(Bt, K, 0, N - 1, k0, base + 8192);
    };

    const int nt = K >> 6;
    STAGE(0, 0);
    __syncthreads();  // drains vmcnt: buf0 ready
    int cur = 0;
    for (int t = 0; t < nt; ++t) {
        if (t + 1 < nt) STAGE(cur ^ 1, (t + 1) * 64);  // overlap with compute below
        char* As = lds + cur * 40960;
        char* Bs = As + 8192;
        bf16x8 af[4][2], bfr[2][2];
#pragma unroll
        for (int mi = 0; mi < 4; ++mi) {
            int r = mi * 16 + l15;
#pragma unroll
            for (int kf = 0; kf < 2; ++kf) {
                int slot = (kf * 4 + kg) ^ (r & 7);
                af[mi][kf] = *(const bf16x8*)(As + r * 128 + slot * 16);
            }
        }
#pragma unroll
        for (int ni = 0; ni < 2; ++ni) {
            int r = wid * 32 + ni * 16 + l15;
#pragma unroll
            for (int kf = 0; kf < 2; ++kf) {
                int slot = (kf * 4 + kg) ^ (r & 7);
                bfr[ni][kf] = *(const bf16x8*)(Bs + r * 128 + slot * 16);
            }
        }
#pragma unroll
        for (int mi = 0; mi < 4; ++mi)
#pragma unroll
            for (int ni = 0; ni < 2; ++ni)
#pragma unroll
                for (int kf = 0; kf < 2; ++kf)
                    acc[mi][ni] = __builtin_amdgcn_mfma_f32_16x16x32_bf16(af[mi][kf], bfr[ni][kf],
                                                                          acc[mi][ni], 0, 0, 0);
        __syncthreads();
        cur ^= 1;
    }

    // C/D layout: col = lane&15, row = (lane>>4)*4 + q
#pragma unroll
    for (int mi = 0; mi < 4; ++mi) {
#pragma unroll
        for (int q = 0; q < 4; ++q) {
            int gr = row0 + mi * 16 + kg * 4 + q;
            if (gr >= M) continue;
            float sc = SCALE ? dinv[gr] : 1.0f;
            int col0 = wid * 32 + l15;
            float v0 = fmaxf(acc[mi][0][q] + bias[col0], 0.f);
            float v1 = fmaxf(acc[mi][1][q] + bias[col0 + 16], 0.f);
            if (SCALE) { v0 *= sc; v1 *= sc; }
            if constexpr (OUT_FP8) {
                int w = __builtin_amdgcn_cvt_pk_fp8_f32(v0, v1, 0, false);
                unsigned char* Cp = (unsigned char*)Cout + (size_t)gr * N;
                Cp[col0] = (unsigned char)(w & 0xff);
                Cp[col0 + 16] = (unsigned char)((w >> 8) & 0xff);
            } else {
                __bf16* Cp = (__bf16*)Cout + (size_t)gr * N;
                Cp[col0] = (__bf16)v0;
                Cp[col0 + 16] = (__bf16)v1;
            }
        }
    }
}

// ---------------- final GEMM: out[M x 64] = A1*B1t^T + A2*B2t^T + bias (f32 out) ----------------
// BM=64, 256 thr = 4 waves (2x2), wave tile 32x32, acc[2][2]; dual-K flattened, dbuf.

__global__ __launch_bounds__(256, 4) void mfma_gemm_final(const __bf16* __restrict__ A1, const __bf16* __restrict__ B1t, int K1,
                                                          const __bf16* __restrict__ A2, const __bf16* __restrict__ B2t, int K2,
                                                          const float* __restrict__ bias, float* __restrict__ Cout, int M) {
    constexpr int N = 64;
    __shared__ alignas(16) char lds[32768];  // 2 x (A 8KB + B 8KB)
    const int lane = threadIdx.x & 63, wid = threadIdx.x >> 6;
    const int wm = wid >> 1, wn = wid & 1;
    const int row0 = blockIdx.x * 64;
    const int kg = lane >> 4, l15 = lane & 15;

    f32x4 acc[2][2];
#pragma unroll
    for (int mi = 0; mi < 2; ++mi)
#pragma unroll
        for (int ni = 0; ni < 2; ++ni) acc[mi][ni] = {0.f, 0.f, 0.f, 0.f};

    const int nt1 = K1 >> 6, nt = nt1 + (K2 >> 6);
    auto STAGE = [&](int buf, int tile) {
        const __bf16* A = (tile < nt1) ? A1 : A2;
        const __bf16* Bt = (tile < nt1) ? B1t : B2t;
        int K = (tile < nt1) ? K1 : K2;
        int k0 = ((tile < nt1) ? tile : tile - nt1) * 64;
        char* base = lds + buf * 16384;
        stage_tile<64, 256>(A, K, row0, M - 1, k0, base);
        stage_tile<64, 256>(Bt, K, 0, N - 1, k0, base + 8192);
    };

    STAGE(0, 0);
    __syncthreads();
    int cur = 0;
    for (int t = 0; t < nt; ++t) {
        if (t + 1 < nt) STAGE(cur ^ 1, t + 1);
        char* As = lds + cur * 16384;
        char* Bs = As + 8192;
        bf16x8 af[2][2], bfr[2][2];
#pragma unroll
        for (int mi = 0; mi < 2; ++mi) {
            int r = wm * 32 + mi * 16 + l15;
#pragma unroll
            for (int kf = 0; kf < 2; ++kf) {
                int slot = (kf * 4 + kg) ^ (r & 7);
                af[mi][kf] = *(const bf16x8*)(As + r * 128 + slot * 16);
            }
        }
#pragma unroll
        for (int ni = 0; ni < 2; ++ni) {
            int r = wn * 32 + ni * 16 + l15;
#pragma unroll
            for (int kf = 0; kf < 2; ++kf) {
                int slot = (kf * 4 + kg) ^ (r & 7);
                bfr[ni][kf] = *(const bf16x8*)(Bs + r * 128 + slot * 16);
            }
        }
#pragma unroll
        for (int mi = 0; mi < 2; ++mi)
#pragma unroll
            for (int ni = 0; ni < 2; ++ni)
#pragma unroll
                for (int kf = 0; kf < 2; ++kf)
                    acc[mi][ni] = __builtin_amdgcn_mfma_f32_16x16x32_bf16(af[mi][kf], bfr[ni][kf],
                                                                          acc[mi][ni], 0, 0, 0);
        __syncthreads();
        cur ^= 1;
    }

#pragma unroll
    for (int mi = 0; mi < 2; ++mi) {
#pragma unroll
        for (int ni = 0; ni < 2; ++ni) {
            int col = wn * 32 + ni * 16 + l15;
            float bv = bias[col];
#pragma unroll
            for (int q = 0; q < 4; ++q) {
                int gr = row0 + wm * 32 + mi * 16 + kg * 4 + q;
                if (gr < M) Cout[(size_t)gr * N + col] = acc[mi][ni][q] + bv;
            }
        }
    }
}

// ---------------- launch ----------------

extern "C" void kernel_launch(void* const* d_in, const int* in_sizes, int n_in,
                              void* d_out, int out_size, void* d_ws, size_t ws_size,
                              hipStream_t stream) {
    const float* x  = (const float*)d_in[0];
    const int*   ei = (const int*)d_in[1];
    const int*   src = ei;
    const int*   dst = ei + N_EDGES;
    const float* W1 = (const float*)d_in[2];
    const float* b1 = (const float*)d_in[3];
    const float* W2 = (const float*)d_in[4];
    const float* b2 = (const float*)d_in[5];
    const float* Wf = (const float*)d_in[6];
    const float* bf = (const float*)d_in[7];
    const float* Ws = (const float*)d_in[8];
    const float* bs = (const float*)d_in[9];
    float* out = (float*)d_out;

    char* ws = (char*)d_ws;
    size_t off = 0;
    auto alloc = [&](size_t bytes) -> void* {
        void* p = ws + off;
        off += (bytes + 255) & ~(size_t)255;
        return p;
    };
    int*           deg      = (int*)alloc(N_NODES * 4);
    int*           rank     = (int*)alloc(N_EDGES * 4);   // per-edge rank within dst bucket
    int*           rowptr   = (int*)alloc((N_NODES + 1) * 4);
    float*         dinv     = (float*)alloc(N_NODES * 4);
    int*           blocksum = (int*)alloc(4096);
    int*           csr      = (int*)alloc(N_EDGES * 4);
    __bf16*        x_bf     = (__bf16*)alloc((size_t)N_NODES * 128 * 2);  // unscaled (skip GEMM)
    __bf16*        x_s      = (__bf16*)alloc((size_t)N_NODES * 128 * 2);  // dinv-scaled (agg1 input)
    __bf16*        W1t      = (__bf16*)alloc(128 * 256 * 2);
    __bf16*        W2t      = (__bf16*)alloc(256 * 256 * 2);
    __bf16*        Wft      = (__bf16*)alloc(256 * 64 * 2);
    __bf16*        Wst      = (__bf16*)alloc(128 * 64 * 2);
    float*         bfinal   = (float*)alloc(64 * 4);
    __bf16*        bufP1    = (__bf16*)alloc((size_t)N_NODES * 256 * 2);  // agg1 out (128-wide), later h2
    unsigned char* bufP2    = (unsigned char*)alloc((size_t)N_NODES * 256);  // h1_s in fp8 e4m3
    __bf16*        bufP3    = (__bf16*)alloc((size_t)N_NODES * 256 * 2);  // agg2 out (bf16)

    zero_deg<<<(N_NODES / 4 + 255) / 256, 256, 0, stream>>>((int4*)deg, N_NODES / 4);

    // hist+rank (atomic-bound) co-scheduled with graph-independent prep
    mega_prep<<<HB + PREP_BLOCKS, 256, 0, stream>>>(dst, deg, rank, x, x_bf,
                                                    W1, W2, Wf, Ws, bf, bs,
                                                    W1t, W2t, Wft, Wst, bfinal);

    scan_partial_dinv<<<SCAN_NB, 512, 0, stream>>>(deg, N_NODES, rowptr, blocksum, dinv);

    // rowptr finalize co-scheduled with x_s = dinv * x_bf
    scan_add_xs<<<SCAN_NB + XS_BLOCKS, 512, 0, stream>>>(rowptr, N_NODES, blocksum, SCAN_NB, N_EDGES,
                                                         x_bf, dinv, x_s);

    // CSR scatter (no atomics)
    fill_csr<<<HB, 256, 0, stream>>>(src, dst, rank, rowptr, csr);

    const int gm64 = (N_NODES + 63) / 64;  // 782

    // layer 1: agg1 = Ahat x (pre-scaled x_s); h1_s = fp8(dinv * relu(agg1 @ W1 + b1))
    aggregate_half<128><<<(N_NODES + 3) / 4, 256, 0, stream>>>(x_s, bufP1, rowptr, csr, dinv);
    mfma_gemm_wide<true, true><<<gm64, 512, 0, stream>>>(bufP1, W1t, 128, b1, dinv, bufP2, N_NODES);

    // layer 2: agg2 = dinv * (sum of fp8 h1_s + self); h2 = relu(agg2 @ W2 + b2)
    aggregate_fp8<<<(N_NODES + 3) / 4, 256, 0, stream>>>(bufP2, bufP3, rowptr, csr, dinv);
    mfma_gemm_wide<false, false><<<gm64, 512, 0, stream>>>(bufP3, W2t, 256, b2, nullptr, bufP1, N_NODES);

    // out = h2 @ Wf + x @ Ws + (bf + bs)
    mfma_gemm_final<<<gm64, 256, 0, stream>>>(bufP1, Wft, 256, x_bf, Wst, 128, bfinal, out, N_NODES);
}

// Round 16
// 183.840 us; speedup vs baseline: 1.5809x; 1.0405x over previous
//
#include <hip/hip_runtime.h>

#define N_NODES 50000
#define N_EDGES 800000
#define HB 782  // hist/fill blocks: 800000/4/256 rounded up

typedef float f32x4 __attribute__((ext_vector_type(4)));
typedef float f32x2 __attribute__((ext_vector_type(2)));
typedef __bf16 bf16x8 __attribute__((ext_vector_type(8)));
typedef __bf16 bf16x4 __attribute__((ext_vector_type(4)));

// ---------------- graph preprocessing ----------------

// custom zero-fill (rocclr fill kernel measured 40us for 200KB)
__global__ void zero_deg(int4* __restrict__ p, int n4) {
    int i = blockIdx.x * blockDim.x + threadIdx.x;
    if (i < n4) p[i] = make_int4(0, 0, 0, 0);
}

#define CAST_N4 (N_NODES * 32)  // float4 count of x
#define PREP_ITEMS (CAST_N4 + 32768 + 65536 + 16384 + 8192 + 64)
#define PREP_BLOCKS ((PREP_ITEMS + 255) / 256)

// MEGA-PREP: blocks [0,HB) do hist+rank (fabric-atomic bound, ~0% VALU/HBM);
// blocks [HB,..) do graph-independent prep hidden under the atomic shadow.
__global__ void mega_prep(const int* __restrict__ dst, int* __restrict__ deg,
                          int* __restrict__ rank,
                          const float* __restrict__ x, __bf16* __restrict__ x_bf,
                          const float* __restrict__ W1, const float* __restrict__ W2,
                          const float* __restrict__ Wf, const float* __restrict__ Ws,
                          const float* __restrict__ bfb, const float* __restrict__ bsb,
                          __bf16* __restrict__ W1t, __bf16* __restrict__ W2t,
                          __bf16* __restrict__ Wft, __bf16* __restrict__ Wst,
                          float* __restrict__ bfinal) {
    int b = blockIdx.x;
    if (b < HB) {
        int i = (b * 256 + threadIdx.x) * 4;
        if (i >= N_EDGES) return;
        int4 d = *(const int4*)(dst + i);
        int4 r;
        r.x = atomicAdd(&deg[d.x], 1);
        r.y = atomicAdd(&deg[d.y], 1);
        r.z = atomicAdd(&deg[d.z], 1);
        r.w = atomicAdd(&deg[d.w], 1);
        *(int4*)(rank + i) = r;
        return;
    }
    int idx = (b - HB) * 256 + threadIdx.x;
    if (idx < CAST_N4) {
        float4 v = ((const float4*)x)[idx];
        bf16x4 a = {(__bf16)v.x, (__bf16)v.y, (__bf16)v.z, (__bf16)v.w};
        __builtin_nontemporal_store(a, (bf16x4*)x_bf + idx);
        return;
    }
    int j = idx - CAST_N4;
    if (j < 32768) {                       // W1t[n*128+k] = W1[k*256+n]
        int n = j >> 7, k = j & 127;
        W1t[j] = (__bf16)W1[k * 256 + n];
    } else if (j < 32768 + 65536) {        // W2t[n*256+k] = W2[k*256+n]
        int i = j - 32768;
        int n = i >> 8, k = i & 255;
        W2t[i] = (__bf16)W2[k * 256 + n];
    } else if (j < 32768 + 65536 + 16384) {  // Wft[n*256+k] = Wf[k*64+n]
        int i = j - (32768 + 65536);
        int n = i >> 8, k = i & 255;
        Wft[i] = (__bf16)Wf[k * 64 + n];
    } else if (j < 32768 + 65536 + 16384 + 8192) {  // Wst[n*128+k] = Ws[k*64+n]
        int i = j - (32768 + 65536 + 16384);
        int n = i >> 7, k = i & 127;
        Wst[i] = (__bf16)Ws[k * 64 + n];
    } else if (j < 32768 + 65536 + 16384 + 8192 + 64) {
        int i = j - (32768 + 65536 + 16384 + 8192);
        bfinal[i] = bfb[i] + bsb[i];
    }
}

__device__ __forceinline__ int wave_incl_scan(int x) {
    int lane = threadIdx.x & 63;
#pragma unroll
    for (int off = 1; off < 64; off <<= 1) {
        int y = __shfl_up(x, off, 64);
        if (lane >= off) x += y;
    }
    return x;
}

// exclusive-scan partials over 512-chunks; also emits dinv = rsqrt(deg+1)
__global__ void scan_partial_dinv(const int* __restrict__ in, int n,
                                  int* __restrict__ out_partial, int* __restrict__ blocksum,
                                  float* __restrict__ dinv) {
    __shared__ int wsum[8];
    int i = blockIdx.x * 512 + threadIdx.x;
    int v = (i < n) ? in[i] : 0;
    if (i < n) dinv[i] = rsqrtf((float)(v + 1));  // +1 self-loop
    int inc = wave_incl_scan(v);
    int lane = threadIdx.x & 63, wid = threadIdx.x >> 6;
    if (lane == 63) wsum[wid] = inc;
    __syncthreads();
    if (wid == 0) {
        int w = (lane < 8) ? wsum[lane] : 0;
        int wi = wave_incl_scan(w);
        if (lane < 8) wsum[lane] = wi;
    }
    __syncthreads();
    int woff = (wid == 0) ? 0 : wsum[wid - 1];
    if (i < n) out_partial[i] = woff + inc - v;
    if (threadIdx.x == 0) blocksum[blockIdx.x] = wsum[7];
}

#define SCAN_NB 98  // (50000+511)/512
#define XS_ITEMS (N_NODES * 16)  // 8-element groups of x (6.4M/8)
#define XS_BLOCKS ((XS_ITEMS + 511) / 512)

// fused: blocks [0,SCAN_NB) finalize rowptr; blocks [SCAN_NB,..) compute
// x_s8 = fp8(dinv * x_bf) -- the layer-1 gather payload, now 1 B/elem.
__global__ __launch_bounds__(512) void scan_add_xs(int* __restrict__ rowptr, int n,
                                                   const int* __restrict__ blocksum, int nb, int total,
                                                   const __bf16* __restrict__ x_bf,
                                                   const float* __restrict__ dinv,
                                                   unsigned char* __restrict__ x_s8) {
    int b = blockIdx.x;
    if (b < SCAN_NB) {
        __shared__ int sexc[128];
        __shared__ int w0tot;
        int t = threadIdx.x;
        if (t < 128) {
            int v = (t < nb) ? blocksum[t] : 0;
            int inc = wave_incl_scan(v);
            sexc[t] = inc - v;  // wave-exclusive
            if (t == 63) w0tot = inc;
        }
        __syncthreads();
        int boff = sexc[b] + (b >= 64 ? w0tot : 0);
        int i = b * 512 + t;
        if (i < n) rowptr[i] += boff;
        if (i == 0) rowptr[n] = total;
        return;
    }
    int j = (b - SCAN_NB) * 512 + threadIdx.x;
    if (j < XS_ITEMS) {
        bf16x8 v = ((const bf16x8*)x_bf)[j];
        float di = dinv[j >> 4];  // 16 groups of 8 per 128-wide row
        float f[8];
#pragma unroll
        for (int k = 0; k < 8; ++k) f[k] = di * (float)v[k];
        int w0 = __builtin_amdgcn_cvt_pk_fp8_f32(f[0], f[1], 0, false);
        w0 = __builtin_amdgcn_cvt_pk_fp8_f32(f[2], f[3], w0, true);
        int w1 = __builtin_amdgcn_cvt_pk_fp8_f32(f[4], f[5], 0, false);
        w1 = __builtin_amdgcn_cvt_pk_fp8_f32(f[6], f[7], w1, true);
        ((uint2*)x_s8)[j] = make_uint2((unsigned)w0, (unsigned)w1);
    }
}

// fill_csr: NO atomics, pos = rowptr[d] + rank[e]. Pure scatter.
__global__ void fill_csr(const int* __restrict__ src, const int* __restrict__ dst,
                         const int* __restrict__ rank,
                         const int* __restrict__ rowptr, int* __restrict__ csr_src) {
    int i = (blockIdx.x * blockDim.x + threadIdx.x) * 4;
    if (i >= N_EDGES) return;
    int4 d = *(const int4*)(dst + i);
    int4 s = *(const int4*)(src + i);
    int4 r = *(const int4*)(rank + i);
    csr_src[rowptr[d.x] + r.x] = s.x;
    csr_src[rowptr[d.y] + r.y] = s.y;
    csr_src[rowptr[d.z] + r.z] = s.z;
    csr_src[rowptr[d.w] + r.w] = s.w;
}

// ---------------- aggregation (fp8 e4m3 payload), templated on F ----------------
// Half-wave: 32 lanes x (F/32) B cover one row; one load gathers TWO edges' rows.
// Decode via v_cvt_pk_f32_fp8; f32 accumulate; bf16 out. 16-edge unroll.

template <int F> struct LdSel;
template <> struct LdSel<128> { using T = unsigned int; };  // 4 B/lane
template <> struct LdSel<256> { using T = uint2; };         // 8 B/lane

template <int F>
__global__ __launch_bounds__(256) void aggregate_fp8(const unsigned char* __restrict__ in_s, __bf16* __restrict__ out,
                                                     const int* __restrict__ rowptr, const int* __restrict__ csr_src,
                                                     const float* __restrict__ dinv) {
    constexpr int BPL = F / 32;  // bytes (=elems) per lane
    using LT = typename LdSel<F>::T;
    int node = blockIdx.x * 4 + (threadIdx.x >> 6);
    int lane = threadIdx.x & 63;
    int lh = lane & 31;
    int half = lane >> 5;
    const unsigned char* colbase = in_s + lh * BPL;

    float acc[BPL] = {};
    auto decode_acc = [&](LT v) {
        if constexpr (BPL == 4) {
            f32x2 p0 = __builtin_amdgcn_cvt_pk_f32_fp8(v, false);
            f32x2 p1 = __builtin_amdgcn_cvt_pk_f32_fp8(v, true);
            acc[0] += p0[0]; acc[1] += p0[1]; acc[2] += p1[0]; acc[3] += p1[1];
        } else {
            f32x2 p0 = __builtin_amdgcn_cvt_pk_f32_fp8(v.x, false);
            f32x2 p1 = __builtin_amdgcn_cvt_pk_f32_fp8(v.x, true);
            f32x2 p2 = __builtin_amdgcn_cvt_pk_f32_fp8(v.y, false);
            f32x2 p3 = __builtin_amdgcn_cvt_pk_f32_fp8(v.y, true);
            acc[0] += p0[0]; acc[1] += p0[1]; acc[2] += p1[0]; acc[3] += p1[1];
            acc[4] += p2[0]; acc[5] += p2[1]; acc[6] += p3[0]; acc[7] += p3[1];
        }
    };

    if (half == 0) decode_acc(*(const LT*)(colbase + (size_t)node * F));

    int beg = rowptr[node], end = rowptr[node + 1];
    int e = beg;
    for (; e + 16 <= end; e += 16) {  // 8 gathers in flight per half-wave
        int ss[8];
#pragma unroll
        for (int k = 0; k < 8; ++k) ss[k] = csr_src[e + 2 * k + half];
        LT v[8];
#pragma unroll
        for (int k = 0; k < 8; ++k) v[k] = *(const LT*)(colbase + (size_t)ss[k] * F);
#pragma unroll
        for (int k = 0; k < 8; ++k) decode_acc(v[k]);
    }
    for (; e + 8 <= end; e += 8) {
        int s0 = csr_src[e + half], s1 = csr_src[e + 2 + half];
        int s2 = csr_src[e + 4 + half], s3 = csr_src[e + 6 + half];
        LT v0 = *(const LT*)(colbase + (size_t)s0 * F);
        LT v1 = *(const LT*)(colbase + (size_t)s1 * F);
        LT v2 = *(const LT*)(colbase + (size_t)s2 * F);
        LT v3 = *(const LT*)(colbase + (size_t)s3 * F);
        decode_acc(v0); decode_acc(v1); decode_acc(v2); decode_acc(v3);
    }
    for (; e + 2 <= end; e += 2) {
        int s = csr_src[e + half];
        decode_acc(*(const LT*)(colbase + (size_t)s * F));
    }
    if (e < end && half == 0) decode_acc(*(const LT*)(colbase + (size_t)csr_src[e] * F));

    float di = dinv[node];
    if constexpr (BPL == 4) {
        bf16x4 o;
#pragma unroll
        for (int j = 0; j < 4; ++j) {
            float t = acc[j] + __shfl_xor(acc[j], 32);
            o[j] = (__bf16)(di * t);
        }
        if (half == 0) __builtin_nontemporal_store(o, (bf16x4*)(out + (size_t)node * F + lh * 4));
    } else {
        bf16x8 o;
#pragma unroll
        for (int j = 0; j < 8; ++j) {
            float t = acc[j] + __shfl_xor(acc[j], 32);
            o[j] = (__bf16)(di * t);
        }
        if (half == 0) __builtin_nontemporal_store(o, (bf16x8*)(out + (size_t)node * F + lh * 8));
    }
}

// ---------------- MFMA bf16 GEMM staging (shared) ----------------
// LDS rows of 64 bf16 (8 x 16B granules), granule slot XOR-swizzled with (row&7).
// global_load_lds writes linearly; global SOURCE address pre-swizzled with the same
// involution so the swizzled read matches (rule 21).

template <int NROWS, int NTH>
__device__ __forceinline__ void stage_tile(const __bf16* __restrict__ src, int K, int row0, int rowclamp,
                                           int k0, char* lds) {
    int t = threadIdx.x;
#pragma unroll
    for (int p = 0; p < NROWS * 8 / NTH; ++p) {
        int G = p * NTH + t;
        int r = G >> 3, gp = G & 7;
        int g = gp ^ (r & 7);
        int gr = row0 + r;
        if (gr > rowclamp) gr = rowclamp;
        const __bf16* sp = src + (size_t)gr * K + k0 + g * 8;
        __builtin_amdgcn_global_load_lds((const __attribute__((address_space(1))) void*)sp,
                                         (__attribute__((address_space(3))) void*)(lds + G * 16), 16, 0, 0);
    }
}

// ---------------- wide GEMM: C[M x 256] = A[M x K] * Bt[256 x K]^T ----------------
// BM=64, 512 thr = 8 waves (1x8), wave tile 64x32, acc[4][2]; 2-phase dbuf.
// OUT_FP8: epilogue packs dinv*relu(.) pairs via v_cvt_pk_fp8_f32, byte stores.

template <bool SCALE, bool OUT_FP8>
__global__ __launch_bounds__(512, 4) void mfma_gemm_wide(const __bf16* __restrict__ A, const __bf16* __restrict__ Bt,
                                                         int K, const float* __restrict__ bias,
                                                         const float* __restrict__ dinv,
                                                         void* __restrict__ Cout, int M) {
    constexpr int N = 256;
    __shared__ alignas(16) char lds[81920];  // 2 x (A 8KB + B 32KB)
    const int lane = threadIdx.x & 63, wid = threadIdx.x >> 6;  // wid = wave col (0..7)
    const int row0 = blockIdx.x * 64;
    const int kg = lane >> 4, l15 = lane & 15;

    f32x4 acc[4][2];
#pragma unroll
    for (int mi = 0; mi < 4; ++mi)
#pragma unroll
        for (int ni = 0; ni < 2; ++ni) acc[mi][ni] = {0.f, 0.f, 0.f, 0.f};

    auto STAGE = [&](int buf, int k0) {
        char* base = lds + buf * 40960;
        stage_tile<64, 512>(A, K, row0, M - 1, k0, base);
        stage_tile<256, 512>(Bt, K, 0, N - 1, k0, base + 8192);
    };

    const int nt = K >> 6;
    STAGE(0, 0);
    __syncthreads();  // drains vmcnt: buf0 ready
    int cur = 0;
    for (int t = 0; t < nt; ++t) {
        if (t + 1 < nt) STAGE(cur ^ 1, (t + 1) * 64);  // overlap with compute below
        char* As = lds + cur * 40960;
        char* Bs = As + 8192;
        bf16x8 af[4][2], bfr[2][2];
#pragma unroll
        for (int mi = 0; mi < 4; ++mi) {
            int r = mi * 16 + l15;
#pragma unroll
            for (int kf = 0; kf < 2; ++kf) {
                int slot = (kf * 4 + kg) ^ (r & 7);
                af[mi][kf] = *(const bf16x8*)(As + r * 128 + slot * 16);
            }
        }
#pragma unroll
        for (int ni = 0; ni < 2; ++ni) {
            int r = wid * 32 + ni * 16 + l15;
#pragma unroll
            for (int kf = 0; kf < 2; ++kf) {
                int slot = (kf * 4 + kg) ^ (r & 7);
                bfr[ni][kf] = *(const bf16x8*)(Bs + r * 128 + slot * 16);
            }
        }
#pragma unroll
        for (int mi = 0; mi < 4; ++mi)
#pragma unroll
            for (int ni = 0; ni < 2; ++ni)
#pragma unroll
                for (int kf = 0; kf < 2; ++kf)
                    acc[mi][ni] = __builtin_amdgcn_mfma_f32_16x16x32_bf16(af[mi][kf], bfr[ni][kf],
                                                                          acc[mi][ni], 0, 0, 0);
        __syncthreads();
        cur ^= 1;
    }

    // C/D layout: col = lane&15, row = (lane>>4)*4 + q
#pragma unroll
    for (int mi = 0; mi < 4; ++mi) {
#pragma unroll
        for (int q = 0; q < 4; ++q) {
            int gr = row0 + mi * 16 + kg * 4 + q;
            if (gr >= M) continue;
            float sc = SCALE ? dinv[gr] : 1.0f;
            int col0 = wid * 32 + l15;
            float v0 = fmaxf(acc[mi][0][q] + bias[col0], 0.f);
            float v1 = fmaxf(acc[mi][1][q] + bias[col0 + 16], 0.f);
            if (SCALE) { v0 *= sc; v1 *= sc; }
            if constexpr (OUT_FP8) {
                int w = __builtin_amdgcn_cvt_pk_fp8_f32(v0, v1, 0, false);
                unsigned char* Cp = (unsigned char*)Cout + (size_t)gr * N;
                Cp[col0] = (unsigned char)(w & 0xff);
                Cp[col0 + 16] = (unsigned char)((w >> 8) & 0xff);
            } else {
                __bf16* Cp = (__bf16*)Cout + (size_t)gr * N;
                Cp[col0] = (__bf16)v0;
                Cp[col0 + 16] = (__bf16)v1;
            }
        }
    }
}

// ---------------- final GEMM: out[M x 64] = A1*B1t^T + A2*B2t^T + bias (f32 out) ----------------
// BM=64, 256 thr = 4 waves (2x2), wave tile 32x32, acc[2][2]; dual-K flattened, dbuf.

__global__ __launch_bounds__(256, 4) void mfma_gemm_final(const __bf16* __restrict__ A1, const __bf16* __restrict__ B1t, int K1,
                                                          const __bf16* __restrict__ A2, const __bf16* __restrict__ B2t, int K2,
                                                          const float* __restrict__ bias, float* __restrict__ Cout, int M) {
    constexpr int N = 64;
    __shared__ alignas(16) char lds[32768];  // 2 x (A 8KB + B 8KB)
    const int lane = threadIdx.x & 63, wid = threadIdx.x >> 6;
    const int wm = wid >> 1, wn = wid & 1;
    const int row0 = blockIdx.x * 64;
    const int kg = lane >> 4, l15 = lane & 15;

    f32x4 acc[2][2];
#pragma unroll
    for (int mi = 0; mi < 2; ++mi)
#pragma unroll
        for (int ni = 0; ni < 2; ++ni) acc[mi][ni] = {0.f, 0.f, 0.f, 0.f};

    const int nt1 = K1 >> 6, nt = nt1 + (K2 >> 6);
    auto STAGE = [&](int buf, int tile) {
        const __bf16* A = (tile < nt1) ? A1 : A2;
        const __bf16* Bt = (tile < nt1) ? B1t : B2t;
        int K = (tile < nt1) ? K1 : K2;
        int k0 = ((tile < nt1) ? tile : tile - nt1) * 64;
        char* base = lds + buf * 16384;
        stage_tile<64, 256>(A, K, row0, M - 1, k0, base);
        stage_tile<64, 256>(Bt, K, 0, N - 1, k0, base + 8192);
    };

    STAGE(0, 0);
    __syncthreads();
    int cur = 0;
    for (int t = 0; t < nt; ++t) {
        if (t + 1 < nt) STAGE(cur ^ 1, t + 1);
        char* As = lds + cur * 16384;
        char* Bs = As + 8192;
        bf16x8 af[2][2], bfr[2][2];
#pragma unroll
        for (int mi = 0; mi < 2; ++mi) {
            int r = wm * 32 + mi * 16 + l15;
#pragma unroll
            for (int kf = 0; kf < 2; ++kf) {
                int slot = (kf * 4 + kg) ^ (r & 7);
                af[mi][kf] = *(const bf16x8*)(As + r * 128 + slot * 16);
            }
        }
#pragma unroll
        for (int ni = 0; ni < 2; ++ni) {
            int r = wn * 32 + ni * 16 + l15;
#pragma unroll
            for (int kf = 0; kf < 2; ++kf) {
                int slot = (kf * 4 + kg) ^ (r & 7);
                bfr[ni][kf] = *(const bf16x8*)(Bs + r * 128 + slot * 16);
            }
        }
#pragma unroll
        for (int mi = 0; mi < 2; ++mi)
#pragma unroll
            for (int ni = 0; ni < 2; ++ni)
#pragma unroll
                for (int kf = 0; kf < 2; ++kf)
                    acc[mi][ni] = __builtin_amdgcn_mfma_f32_16x16x32_bf16(af[mi][kf], bfr[ni][kf],
                                                                          acc[mi][ni], 0, 0, 0);
        __syncthreads();
        cur ^= 1;
    }

#pragma unroll
    for (int mi = 0; mi < 2; ++mi) {
#pragma unroll
        for (int ni = 0; ni < 2; ++ni) {
            int col = wn * 32 + ni * 16 + l15;
            float bv = bias[col];
#pragma unroll
            for (int q = 0; q < 4; ++q) {
                int gr = row0 + wm * 32 + mi * 16 + kg * 4 + q;
                if (gr < M) Cout[(size_t)gr * N + col] = acc[mi][ni][q] + bv;
            }
        }
    }
}

// ---------------- launch ----------------

extern "C" void kernel_launch(void* const* d_in, const int* in_sizes, int n_in,
                              void* d_out, int out_size, void* d_ws, size_t ws_size,
                              hipStream_t stream) {
    const float* x  = (const float*)d_in[0];
    const int*   ei = (const int*)d_in[1];
    const int*   src = ei;
    const int*   dst = ei + N_EDGES;
    const float* W1 = (const float*)d_in[2];
    const float* b1 = (const float*)d_in[3];
    const float* W2 = (const float*)d_in[4];
    const float* b2 = (const float*)d_in[5];
    const float* Wf = (const float*)d_in[6];
    const float* bf = (const float*)d_in[7];
    const float* Ws = (const float*)d_in[8];
    const float* bs = (const float*)d_in[9];
    float* out = (float*)d_out;

    char* ws = (char*)d_ws;
    size_t off = 0;
    auto alloc = [&](size_t bytes) -> void* {
        void* p = ws + off;
        off += (bytes + 255) & ~(size_t)255;
        return p;
    };
    int*           deg      = (int*)alloc(N_NODES * 4);
    int*           rank     = (int*)alloc(N_EDGES * 4);   // per-edge rank within dst bucket
    int*           rowptr   = (int*)alloc((N_NODES + 1) * 4);
    float*         dinv     = (float*)alloc(N_NODES * 4);
    int*           blocksum = (int*)alloc(4096);
    int*           csr      = (int*)alloc(N_EDGES * 4);
    __bf16*        x_bf     = (__bf16*)alloc((size_t)N_NODES * 128 * 2);  // unscaled (skip GEMM)
    unsigned char* x_s8     = (unsigned char*)alloc((size_t)N_NODES * 128);  // fp8 dinv-scaled (agg1)
    __bf16*        W1t      = (__bf16*)alloc(128 * 256 * 2);
    __bf16*        W2t      = (__bf16*)alloc(256 * 256 * 2);
    __bf16*        Wft      = (__bf16*)alloc(256 * 64 * 2);
    __bf16*        Wst      = (__bf16*)alloc(128 * 64 * 2);
    float*         bfinal   = (float*)alloc(64 * 4);
    __bf16*        bufP1    = (__bf16*)alloc((size_t)N_NODES * 256 * 2);  // agg1 out (128-wide), later h2
    unsigned char* bufP2    = (unsigned char*)alloc((size_t)N_NODES * 256);  // h1_s in fp8 e4m3
    __bf16*        bufP3    = (__bf16*)alloc((size_t)N_NODES * 256 * 2);  // agg2 out (bf16)

    zero_deg<<<(N_NODES / 4 + 255) / 256, 256, 0, stream>>>((int4*)deg, N_NODES / 4);

    // hist+rank (atomic-bound) co-scheduled with graph-independent prep
    mega_prep<<<HB + PREP_BLOCKS, 256, 0, stream>>>(dst, deg, rank, x, x_bf,
                                                    W1, W2, Wf, Ws, bf, bs,
                                                    W1t, W2t, Wft, Wst, bfinal);

    scan_partial_dinv<<<SCAN_NB, 512, 0, stream>>>(deg, N_NODES, rowptr, blocksum, dinv);

    // rowptr finalize co-scheduled with x_s8 = fp8(dinv * x_bf)
    scan_add_xs<<<SCAN_NB + XS_BLOCKS, 512, 0, stream>>>(rowptr, N_NODES, blocksum, SCAN_NB, N_EDGES,
                                                         x_bf, dinv, x_s8);

    // CSR scatter (no atomics)
    fill_csr<<<HB, 256, 0, stream>>>(src, dst, rank, rowptr, csr);

    const int gm64 = (N_NODES + 63) / 64;  // 782

    // layer 1: agg1 = Ahat x (fp8 pre-scaled x_s8); h1_s = fp8(dinv * relu(agg1 @ W1 + b1))
    aggregate_fp8<128><<<(N_NODES + 3) / 4, 256, 0, stream>>>(x_s8, bufP1, rowptr, csr, dinv);
    mfma_gemm_wide<true, true><<<gm64, 512, 0, stream>>>(bufP1, W1t, 128, b1, dinv, bufP2, N_NODES);

    // layer 2: agg2 = dinv * (sum of fp8 h1_s + self); h2 = relu(agg2 @ W2 + b2)
    aggregate_fp8<256><<<(N_NODES + 3) / 4, 256, 0, stream>>>(bufP2, bufP3, rowptr, csr, dinv);
    mfma_gemm_wide<false, false><<<gm64, 512, 0, stream>>>(bufP3, W2t, 256, b2, nullptr, bufP1, N_NODES);

    // out = h2 @ Wf + x @ Ws + (bf + bs)
    mfma_gemm_final<<<gm64, 256, 0, stream>>>(bufP1, Wft, 256, x_bf, Wst, 128, bfinal, out, N_NODES);
}